// Round 2
// baseline (18028.416 us; speedup 1.0000x reference)
//
#include <hip/hip_runtime.h>
#include <hip/hip_bf16.h>

// Model dims
// Tx=512 V=100 D=64 DM=512 NH=8 DFF=2048 NL=2 H=256 DATT=128 FCH=256 OUT=2

__device__ __forceinline__ float sigmf(float x) { return 1.f / (1.f + __expf(-x)); }
__device__ __forceinline__ int jglob_of(int e0, int jl) { return ((jl >> 4) << 8) + e0 + (jl & 15); }

// ===================== PE table =====================
__global__ __launch_bounds__(256) void pe_kernel(float* __restrict__ pe) {
  int idx = blockIdx.x * 256 + threadIdx.x;
  if (idx >= 100 * 512) return;
  int v = idx >> 9, n = idx & 511;
  float d = expf(-(float)(n & ~1) * (9.2103403719761836f / 512.0f));
  float ang = (float)v * d;
  pe[idx] = (n & 1) ? cosf(ang) : sinf(ang);
}

// ===================== generic tiled GEMM =====================
// out[r,c] = sum_k A[row(r), k] * W[c, k]   (+bias[c] +extra[(r/extraDiv)*N+c])
// A element offset for row r: aBase + (r/aDiv)*aSA + (r%aDiv)*aSB + k
// out element offset:         oBase + (r/oDiv)*oSA + (r%oDiv)*oSB + c
// addTo: out += value (residual, in-place);  relu: applied after bias
// M multiples of 128, N multiples of 128, K multiples of 16. No bounds checks.
__global__ __launch_bounds__(256) void gemm_kernel(
    const float* __restrict__ A, long aBase, int aDiv, long aSA, long aSB,
    const float* __restrict__ W, int ldw,
    const float* __restrict__ bias,
    const float* __restrict__ extra, int extraDiv,
    float* __restrict__ outF, __hip_bfloat16* __restrict__ outB,
    long oBase, int oDiv, long oSA, long oSB,
    int N, int K, int addTo, int relu)
{
  __shared__ float As[16][132];
  __shared__ float Bs[16][132];
  const int tid = threadIdx.x;
  const int rT = blockIdx.y * 128, nT = blockIdx.x * 128;
  const int lm = tid >> 1;       // row (for A) / col (for W) this thread loads
  const int kq = tid & 1;        // which 8-wide k chunk
  const int r = rT + lm;
  const long arow = aBase + (long)(r / aDiv) * aSA + (long)(r % aDiv) * aSB;
  const long brow = (long)(nT + lm) * ldw;
  const int ty = tid >> 4, tx = tid & 15;

  float acc[8][8];
#pragma unroll
  for (int i = 0; i < 8; ++i)
#pragma unroll
    for (int j = 0; j < 8; ++j) acc[i][j] = 0.f;

  for (int k0 = 0; k0 < K; k0 += 16) {
    const float4 la0 = *(const float4*)(A + arow + k0 + kq * 8);
    const float4 la1 = *(const float4*)(A + arow + k0 + kq * 8 + 4);
    const float4 lb0 = *(const float4*)(W + brow + k0 + kq * 8);
    const float4 lb1 = *(const float4*)(W + brow + k0 + kq * 8 + 4);
    __syncthreads();
    As[kq*8+0][lm] = la0.x; As[kq*8+1][lm] = la0.y; As[kq*8+2][lm] = la0.z; As[kq*8+3][lm] = la0.w;
    As[kq*8+4][lm] = la1.x; As[kq*8+5][lm] = la1.y; As[kq*8+6][lm] = la1.z; As[kq*8+7][lm] = la1.w;
    Bs[kq*8+0][lm] = lb0.x; Bs[kq*8+1][lm] = lb0.y; Bs[kq*8+2][lm] = lb0.z; Bs[kq*8+3][lm] = lb0.w;
    Bs[kq*8+4][lm] = lb1.x; Bs[kq*8+5][lm] = lb1.y; Bs[kq*8+6][lm] = lb1.z; Bs[kq*8+7][lm] = lb1.w;
    __syncthreads();
#pragma unroll
    for (int kk = 0; kk < 16; ++kk) {
      const float4 a0 = *(const float4*)&As[kk][ty * 8];
      const float4 a1 = *(const float4*)&As[kk][ty * 8 + 4];
      const float4 b0 = *(const float4*)&Bs[kk][tx * 8];
      const float4 b1 = *(const float4*)&Bs[kk][tx * 8 + 4];
      const float aa[8] = {a0.x, a0.y, a0.z, a0.w, a1.x, a1.y, a1.z, a1.w};
      const float bb[8] = {b0.x, b0.y, b0.z, b0.w, b1.x, b1.y, b1.z, b1.w};
#pragma unroll
      for (int i = 0; i < 8; ++i)
#pragma unroll
        for (int j = 0; j < 8; ++j)
          acc[i][j] = fmaf(aa[i], bb[j], acc[i][j]);
    }
  }

#pragma unroll
  for (int i = 0; i < 8; ++i) {
    const int rr = rT + ty * 8 + i;
    const long orow = oBase + (long)(rr / oDiv) * oSA + (long)(rr % oDiv) * oSB;
    const long exrow = (long)(rr / extraDiv) * N;
#pragma unroll
    for (int jq = 0; jq < 2; ++jq) {
      const int gc = nT + tx * 8 + jq * 4;
      float v0 = acc[i][jq*4+0], v1 = acc[i][jq*4+1], v2 = acc[i][jq*4+2], v3 = acc[i][jq*4+3];
      if (bias) {
        const float4 bv = *(const float4*)(bias + gc);
        v0 += bv.x; v1 += bv.y; v2 += bv.z; v3 += bv.w;
      }
      if (extra) {
        const float4 ev = *(const float4*)(extra + exrow + gc);
        v0 += ev.x; v1 += ev.y; v2 += ev.z; v3 += ev.w;
      }
      if (relu) { v0 = fmaxf(v0, 0.f); v1 = fmaxf(v1, 0.f); v2 = fmaxf(v2, 0.f); v3 = fmaxf(v3, 0.f); }
      if (outF) {
        float4* op = (float4*)(outF + orow + gc);
        if (addTo) { const float4 ov = *op; v0 += ov.x; v1 += ov.y; v2 += ov.z; v3 += ov.w; }
        float4 sv; sv.x = v0; sv.y = v1; sv.z = v2; sv.w = v3;
        *op = sv;
      } else {
        __hip_bfloat16* op = outB + orow + gc;
        op[0] = __float2bfloat16(v0); op[1] = __float2bfloat16(v1);
        op[2] = __float2bfloat16(v2); op[3] = __float2bfloat16(v3);
      }
    }
  }
}

// ===================== attention (per (head, chunk-local b) block) =====================
// qkv chunk layout: row (v*64 + bl) * 1536, cols: q at h*64, k at 512+h*64, v at 1024+h*64
// writes ctx chunk-local: outY[(v*64 + bl)*512 + h*64 + d]
__global__ __launch_bounds__(256) void attn_kernel(
    const float* __restrict__ qkv, float* __restrict__ outY)
{
  __shared__ float q_s[100][68];
  __shared__ float k_s[100][68];
  __shared__ float v_s[100][68];
  __shared__ float S_s[100][104];
  __shared__ float rs_s[100];
  const int h = blockIdx.x, bl = blockIdx.y, tid = threadIdx.x;

  for (int idx = tid; idx < 100 * 64; idx += 256) {
    int vv = idx >> 6, d = idx & 63;
    long base = ((long)(vv * 64 + bl)) * 1536 + h * 64 + d;
    q_s[vv][d] = qkv[base];
    k_s[vv][d] = qkv[base + 512];
    v_s[vv][d] = qkv[base + 1024];
  }
  __syncthreads();

  const int ty = tid >> 4, tx = tid & 15;
  // scores S = (q k^T) * 0.125
  for (int i0 = 0; i0 < 128; i0 += 64) {
    for (int j0 = 0; j0 < 128; j0 += 64) {
      float acc[4][4];
#pragma unroll
      for (int r = 0; r < 4; ++r)
#pragma unroll
        for (int c = 0; c < 4; ++c) acc[r][c] = 0.f;
      for (int d = 0; d < 64; d += 4) {
        float4 qv[4], kv[4];
#pragma unroll
        for (int r = 0; r < 4; ++r) {
          int ii = i0 + ty * 4 + r; ii = (ii < 100) ? ii : 99;
          qv[r] = *(const float4*)&q_s[ii][d];
        }
#pragma unroll
        for (int c = 0; c < 4; ++c) {
          int jj = j0 + tx * 4 + c; jj = (jj < 100) ? jj : 99;
          kv[c] = *(const float4*)&k_s[jj][d];
        }
#pragma unroll
        for (int r = 0; r < 4; ++r)
#pragma unroll
          for (int c = 0; c < 4; ++c)
            acc[r][c] += qv[r].x * kv[c].x + qv[r].y * kv[c].y + qv[r].z * kv[c].z + qv[r].w * kv[c].w;
      }
#pragma unroll
      for (int r = 0; r < 4; ++r)
#pragma unroll
        for (int c = 0; c < 4; ++c) {
          int ii = i0 + ty * 4 + r, jj = j0 + tx * 4 + c;
          if (ii < 100 && jj < 100) S_s[ii][jj] = acc[r][c] * 0.125f;
        }
    }
  }
  __syncthreads();
  // softmax rows (store exp, keep 1/rowsum)
  if (tid < 100) {
    float m = -1e30f;
    for (int j = 0; j < 100; ++j) m = fmaxf(m, S_s[tid][j]);
    float s = 0.f;
    for (int j = 0; j < 100; ++j) { float e = __expf(S_s[tid][j] - m); S_s[tid][j] = e; s += e; }
    rs_s[tid] = 1.f / s;
  }
  __syncthreads();
  // ctx = softmax @ v
  for (int i0 = 0; i0 < 128; i0 += 64) {
    float acc[4][4];
#pragma unroll
    for (int r = 0; r < 4; ++r)
#pragma unroll
      for (int c = 0; c < 4; ++c) acc[r][c] = 0.f;
    for (int j = 0; j < 100; ++j) {
      float av[4];
#pragma unroll
      for (int r = 0; r < 4; ++r) {
        int ii = i0 + ty * 4 + r; ii = (ii < 100) ? ii : 99;
        av[r] = S_s[ii][j];
      }
      const float4 vv4 = *(const float4*)&v_s[j][tx * 4];
#pragma unroll
      for (int r = 0; r < 4; ++r) {
        acc[r][0] += av[r] * vv4.x; acc[r][1] += av[r] * vv4.y;
        acc[r][2] += av[r] * vv4.z; acc[r][3] += av[r] * vv4.w;
      }
    }
#pragma unroll
    for (int r = 0; r < 4; ++r) {
      int ii = i0 + ty * 4 + r;
      if (ii < 100) {
        float inv = rs_s[ii];
        float4 o; o.x = acc[r][0] * inv; o.y = acc[r][1] * inv; o.z = acc[r][2] * inv; o.w = acc[r][3] * inv;
        *(float4*)(outY + ((long)ii * 64 + bl) * 512 + h * 64 + tx * 4) = o;
      }
    }
  }
}

// ===================== layernorm (in-place, one wave per row of 512) =====================
__global__ __launch_bounds__(256) void ln_kernel(float* __restrict__ X,
    const float* __restrict__ g, const float* __restrict__ b)
{
  const int row = blockIdx.x * 4 + (threadIdx.x >> 6);
  const int lane = threadIdx.x & 63;
  float* x = X + (long)row * 512;
  float v[8]; float s = 0.f, sq = 0.f;
#pragma unroll
  for (int i = 0; i < 8; ++i) { v[i] = x[lane + i * 64]; s += v[i]; sq += v[i] * v[i]; }
#pragma unroll
  for (int off = 32; off; off >>= 1) { s += __shfl_xor(s, off, 64); sq += __shfl_xor(sq, off, 64); }
  const float mean = s * (1.f / 512.f);
  const float var = sq * (1.f / 512.f) - mean * mean;
  const float inv = rsqrtf(var + 1e-5f);
#pragma unroll
  for (int i = 0; i < 8; ++i) {
    int c = lane + i * 64;
    x[c] = (v[i] - mean) * inv * g[c] + b[c];
  }
}

// ===================== decoder init =====================
__global__ void init_kernel(float* s_h_g, float* a2_g, float* c_g, unsigned* cnt) {
  int t = threadIdx.x;
  if (t == 0) *cnt = 0u;
  s_h_g[t] = 0.f;
  if (t < 128) a2_g[t] = 0.f;
  c_g[t] = 0.f; c_g[256 + t] = 0.f;
}

// ===================== decoder: 512-step attention-LSTM scan =====================
// 16 persistent blocks, device-scope spin barrier (2 barriers/step).
// Block i owns LSTM elements e in [i*16, i*16+16) -> gate rows {e, 256+e, 512+e, 768+e}.
#define DEC_NB 16

__device__ __forceinline__ void gbar(unsigned* cnt, unsigned* gen) {
  __syncthreads();
  ++(*gen);
  if (threadIdx.x == 0) {
    __hip_atomic_fetch_add(cnt, 1u, __ATOMIC_ACQ_REL, __HIP_MEMORY_SCOPE_AGENT);
    const unsigned tgt = (*gen) * (unsigned)DEC_NB;
    while (__hip_atomic_load(cnt, __ATOMIC_ACQUIRE, __HIP_MEMORY_SCOPE_AGENT) < tgt)
      __builtin_amdgcn_s_sleep(2);
  }
  __syncthreads();
}

__global__ __launch_bounds__(256) void decoder_kernel(
    const float* __restrict__ X,            // [V*Tx, 512] transformer output
    const __hip_bfloat16* __restrict__ Pb,  // [512*100, 128] h @ W1a^T (bf16)
    const __hip_bfloat16* __restrict__ Gb,  // [512*100, 1024] h @ Wih^T (bf16)
    const float* __restrict__ att1_w, const float* __restrict__ att1_b,
    const float* __restrict__ att2_w,
    const float* __restrict__ whh,
    const float* __restrict__ bih, const float* __restrict__ bhh,
    const float* __restrict__ fc1_w, const float* __restrict__ fc1_b,
    const float* __restrict__ fc2_w, const float* __restrict__ fc2_b,
    float* s_h_g, float* a2_g, float* c_g, unsigned* cnt,
    float* __restrict__ out)
{
  const int tid = threadIdx.x;
  const int blk = blockIdx.x;
  const int e0 = blk * 16;

  __shared__ float Whh_s[64][257];               // this block's 64 gate rows of Whh
  __shared__ __hip_bfloat16 W1b_s[128][257];     // att1_w[:, 512:768] (bf16)
  __shared__ float w2_s[128], ub_s[128], bsum_s[64];
  __shared__ float u_s[128], hh_s[64], s_h_s[256], sc_s[16];
  __shared__ float a2_s[128];
  __shared__ float red_s[256];
  __shared__ float gates_s[64];
  __shared__ float red4_s[4];
  __shared__ float fcin_s[768];
  __shared__ float fca_s[256];

  // ---- one-time LDS staging ----
  for (int idx = tid; idx < 64 * 256; idx += 256) {
    int jl = idx >> 8, k = idx & 255;
    Whh_s[jl][k] = whh[(long)jglob_of(e0, jl) * 256 + k];
  }
  for (int idx = tid; idx < 128 * 256; idx += 256) {
    int j = idx >> 8, k = idx & 255;
    W1b_s[j][k] = __float2bfloat16(att1_w[(long)j * 768 + 512 + k]);
  }
  if (tid < 128) { w2_s[tid] = att2_w[tid]; ub_s[tid] = att1_b[tid]; }
  if (tid < 64) {
    int jg = jglob_of(e0, tid);
    bsum_s[tid] = bih[jg] + bhh[jg];
  }
  if (tid < 16) sc_s[tid] = 0.f;
  if (tid < 16)
    __hip_atomic_store(&s_h_g[e0 + tid], 0.f, __ATOMIC_RELAXED, __HIP_MEMORY_SCOPE_AGENT);
  unsigned gen = 0;
  gbar(cnt, &gen);

  const int vg = tid >> 6;        // 0..3 (v-quarter for G dot)
  const int jl64 = tid & 63;      // gate-row-local index for G dot
  const int hi = tid >> 7;        // 0/1 (which of the pass's two v's)
  const int jp = tid & 127;       // DATT index
  const int Gjg = jglob_of(e0, jl64);
  float pg[25];

  for (int t = 0; t < 512; ++t) {
    // ======== phase A (needs s_h(t-1)) ========
    const __hip_bfloat16* Grow = Gb + (long)t * 102400 + Gjg;
#pragma unroll
    for (int i = 0; i < 25; ++i)
      pg[i] = __bfloat162float(Grow[(long)(vg * 25 + i) * 1024]);

    float pv[4];
#pragma unroll
    for (int i = 0; i < 4; ++i) {
      int m = 2 * i + hi;
      int v = blk + 16 * m;
      int vv = (v < 100) ? v : 0;
      pv[i] = __bfloat162float(Pb[((long)t * 100 + vv) * 128 + jp]);
    }

    s_h_s[tid] = __hip_atomic_load(&s_h_g[tid], __ATOMIC_RELAXED, __HIP_MEMORY_SCOPE_AGENT);
    __syncthreads();

    // u[j] = W1b[j,:] . s_h + att1_b[j]   (redundant per block; j = tid>>1, halves of k)
    {
      const int j = tid >> 1, h2 = tid & 1;
      float acc = 0.f;
      for (int k = 0; k < 128; ++k)
        acc += __bfloat162float(W1b_s[j][h2 * 128 + k]) * s_h_s[h2 * 128 + k];
      acc += __shfl_xor(acc, 1, 64);
      if (h2 == 0) u_s[j] = acc + ub_s[j];
    }
    // gates_hh[jl] = Whh[jg(jl),:] . s_h  (jl = tid>>2, quarters of k)
    {
      const int jl = tid >> 2, q = tid & 3;
      float acc = 0.f;
      for (int k = 0; k < 64; ++k)
        acc += Whh_s[jl][q * 64 + k] * s_h_s[q * 64 + k];
      acc += __shfl_xor(acc, 1, 64);
      acc += __shfl_xor(acc, 2, 64);
      if (q == 0) hh_s[jl] = acc;
    }
    __syncthreads();

    // a2[v] = sum_j tanh(P[t,v,j] + u[j]) * w2[j]   for this block's v's
#pragma unroll
    for (int i = 0; i < 4; ++i) {
      const int m = 2 * i + hi;
      const int v = blk + 16 * m;
      float val = 0.f;
      if (v < 100) val = tanhf(pv[i] + u_s[jp]) * w2_s[jp];
#pragma unroll
      for (int off = 32; off; off >>= 1) val += __shfl_xor(val, off, 64);
      if ((tid & 63) == 0) red_s[tid >> 6] = val;
      __syncthreads();
      if (tid == 0 && blk + 32 * i < 100)
        __hip_atomic_store(&a2_g[blk + 32 * i], red_s[0] + red_s[1],
                           __ATOMIC_RELAXED, __HIP_MEMORY_SCOPE_AGENT);
      if (tid == 128 && blk + 32 * i + 16 < 100)
        __hip_atomic_store(&a2_g[blk + 32 * i + 16], red_s[2] + red_s[3],
                           __ATOMIC_RELAXED, __HIP_MEMORY_SCOPE_AGENT);
      __syncthreads();
    }
    gbar(cnt, &gen);

    // ======== phase C (needs all a2) ========
    if (tid < 100)
      a2_s[tid] = __hip_atomic_load(&a2_g[tid], __ATOMIC_RELAXED, __HIP_MEMORY_SCOPE_AGENT);
    __syncthreads();
    if (tid < 64) {
      float m = a2_s[tid];
      if (tid + 64 < 100) m = fmaxf(m, a2_s[tid + 64]);
#pragma unroll
      for (int off = 32; off; off >>= 1) m = fmaxf(m, __shfl_xor(m, off, 64));
      if (tid == 0) red4_s[0] = m;
    }
    __syncthreads();
    const float mx = red4_s[0];
    if (tid < 100) a2_s[tid] = __expf(a2_s[tid] - mx);
    __syncthreads();
    if (tid < 64) {
      float s = a2_s[tid] + ((tid + 64 < 100) ? a2_s[tid + 64] : 0.f);
#pragma unroll
      for (int off = 32; off; off >>= 1) s += __shfl_xor(s, off, 64);
      if (tid == 0) red4_s[1] = s;
    }
    __syncthreads();
    {
      const float inv = 1.f / (red4_s[1] + 1e-15f);
      if (tid < 100) a2_s[tid] *= inv;   // alpha
    }
    __syncthreads();

    // gates_ih[jl] = sum_v alpha[v] * G[t,v,jg(jl)]
    {
      float part = 0.f;
#pragma unroll
      for (int i = 0; i < 25; ++i) part += a2_s[vg * 25 + i] * pg[i];
      red_s[tid] = part;
    }
    __syncthreads();
    if (tid < 64) {
      float gv = red_s[tid] + red_s[64 + tid] + red_s[128 + tid] + red_s[192 + tid];
      gates_s[tid] = gv + hh_s[tid] + bsum_s[tid];
    }
    __syncthreads();

    if (t < 511) {
      if (tid < 16) {
        const float ig = gates_s[tid], fg = gates_s[16 + tid];
        const float gg = gates_s[32 + tid], og = gates_s[48 + tid];
        const float sc = sigmf(fg) * sc_s[tid] + sigmf(ig) * tanhf(gg);
        sc_s[tid] = sc;
        const float sh = sigmf(og) * tanhf(sc);
        __hip_atomic_store(&s_h_g[e0 + tid], sh, __ATOMIC_RELAXED, __HIP_MEMORY_SCOPE_AGENT);
      }
    } else {
      // final step: c[d] = sum_v alpha[v] * h[v, d]  (this block: cols [blk*32, blk*32+32))
      const int dl = tid & 31, vs = tid >> 5;
      const int v0 = vs * 13, v1 = (v0 + 13 < 100) ? v0 + 13 : 100;
      float accc = 0.f;
      for (int v = v0; v < v1; ++v)
        accc += a2_s[v] * X[((long)(v * 512 + 511)) * 512 + blk * 32 + dl];
      red_s[tid] = accc;
      __syncthreads();
      if (tid < 32) {
        float cc = 0.f;
#pragma unroll
        for (int s = 0; s < 8; ++s) cc += red_s[s * 32 + tid];
        __hip_atomic_store(&c_g[blk * 32 + tid], cc, __ATOMIC_RELAXED, __HIP_MEMORY_SCOPE_AGENT);
      }
    }
    gbar(cnt, &gen);
  }

  // ======== fc head (block 0 only). s_h_g holds s_h(510) (step 511 skipped the update). ========
  if (blk == 0) {
    fcin_s[tid]       = __hip_atomic_load(&c_g[tid],       __ATOMIC_RELAXED, __HIP_MEMORY_SCOPE_AGENT);
    fcin_s[256 + tid] = __hip_atomic_load(&c_g[256 + tid], __ATOMIC_RELAXED, __HIP_MEMORY_SCOPE_AGENT);
    fcin_s[512 + tid] = __hip_atomic_load(&s_h_g[tid],     __ATOMIC_RELAXED, __HIP_MEMORY_SCOPE_AGENT);
    __syncthreads();
    float acc = fc1_b[tid];
    for (int k = 0; k < 768; ++k) acc += fc1_w[(long)tid * 768 + k] * fcin_s[k];
    fca_s[tid] = fmaxf(acc, 0.f);
    __syncthreads();
    if (tid < 128) {
      const int r = tid >> 6, k0 = tid & 63;
      float a = 0.f;
#pragma unroll
      for (int s = 0; s < 4; ++s) a += fc2_w[r * 256 + k0 + s * 64] * fca_s[k0 + s * 64];
#pragma unroll
      for (int off = 32; off; off >>= 1) a += __shfl_xor(a, off, 64);
      if (k0 == 0) red4_s[r] = a + fc2_b[r];
    }
    __syncthreads();
    if (tid == 0) {
      const float l0 = red4_s[0], l1 = red4_s[1];
      const float m = fmaxf(l0, l1);
      const float ls = logf(__expf(l0 - m) + __expf(l1 - m));
      out[0] = l0 - m - ls;
      out[1] = l1 - m - ls;
    }
  }
}

// ===================== host launch =====================
extern "C" void kernel_launch(void* const* d_in, const int* in_sizes, int n_in,
                              void* d_out, int out_size, void* d_ws, size_t ws_size,
                              hipStream_t stream) {
  const float* x_data  = (const float*)d_in[0];
  const float* feat_w  = (const float*)d_in[1];
  const float* feat_b  = (const float*)d_in[2];
  const float* in_w    = (const float*)d_in[3];
  const float* in_b    = (const float*)d_in[4];
  const float* out_w   = (const float*)d_in[5];
  const float* out_b   = (const float*)d_in[6];
  const float* ff1_w   = (const float*)d_in[7];
  const float* ff1_b   = (const float*)d_in[8];
  const float* ff2_w   = (const float*)d_in[9];
  const float* ff2_b   = (const float*)d_in[10];
  const float* ln1_g   = (const float*)d_in[11];
  const float* ln1_b   = (const float*)d_in[12];
  const float* ln2_g   = (const float*)d_in[13];
  const float* ln2_b   = (const float*)d_in[14];
  const float* att1_w  = (const float*)d_in[15];
  const float* att1_b  = (const float*)d_in[16];
  const float* att2_w  = (const float*)d_in[17];
  // att2_b (d_in[18]) cancels in the softmax — unused
  const float* lstm_wih = (const float*)d_in[19];
  const float* lstm_whh = (const float*)d_in[20];
  const float* lstm_bih = (const float*)d_in[21];
  const float* lstm_bhh = (const float*)d_in[22];
  const float* fc1_w   = (const float*)d_in[23];
  const float* fc1_b   = (const float*)d_in[24];
  const float* fc2_w   = (const float*)d_in[25];
  const float* fc2_b   = (const float*)d_in[26];

  // ---- workspace layout (floats), time-overlaid to fit ~213 MiB ----
  // bufX:   [51200, 512] activations                       26,214,400 f
  // R:      transformer: bufT (13,107,200) + bufY (3,276,800)
  //         decoder-precompute: PbB bf16 [51200,128] (=3,276,800 f)
  //                             GbB bf16 [51200,1024] (=26,214,400 f)
  //         R size = 29,491,200 f
  // pe:     51,200 f ; then s_h/a2/c/cnt
  float* ws   = (float*)d_ws;
  float* bufX = ws;
  float* R    = bufX + 26214400;
  float* bufT = R;                          // qkv chunk [100*64,1536] / FF chunk [6400,2048]
  float* bufY = R + 13107200;               // ctx chunk [100*64,512]
  __hip_bfloat16* PbB = (__hip_bfloat16*)R;                 // [51200,128] bf16
  __hip_bfloat16* GbB = (__hip_bfloat16*)(R + 3276800);     // [51200,1024] bf16
  float* pe    = R + 29491200;
  float* s_h_g = pe + 51200;
  float* a2_g  = s_h_g + 256;
  float* c_g   = a2_g + 128;
  unsigned* cnt = (unsigned*)(c_g + 512);

  pe_kernel<<<200, 256, 0, stream>>>(pe);

  // feature map + PE:  bufX[v*512+b, :] = x_data[b, v, :] @ feat_w^T + feat_b + pe[v, :]
  gemm_kernel<<<dim3(4, 400), 256, 0, stream>>>(
      x_data, 0L, 512, 64L, 6400L, feat_w, 64, feat_b, pe, 512,
      bufX, nullptr, 0L, 1 << 30, 0L, 512L, 512, 64, 0, 0);

  for (int l = 0; l < 2; ++l) {
    for (int c = 0; c < 8; ++c) {
      const long b0 = c * 64;
      // qkv for b in [b0, b0+64): bufT[(v*64+bl), 0:1536]
      gemm_kernel<<<dim3(12, 50), 256, 0, stream>>>(
          bufX, b0 * 512, 64, 262144L, 512L,
          in_w + (long)l * 786432, 512, in_b + l * 1536, nullptr, 1,
          bufT, nullptr, 0L, 1 << 30, 0L, 1536L, 1536, 512, 0, 0);
      attn_kernel<<<dim3(8, 64), 256, 0, stream>>>(bufT, bufY);
      // x += ctx @ out_w^T + out_b   (chunk rows v*64+bl -> bufX rows v*512+b0+bl)
      gemm_kernel<<<dim3(4, 50), 256, 0, stream>>>(
          bufY, 0L, 1 << 30, 0L, 512L,
          out_w + (long)l * 262144, 512, out_b + l * 512, nullptr, 1,
          bufX, nullptr, b0 * 512, 64, 262144L, 512L, 512, 512, 1, 0);
    }
    ln_kernel<<<12800, 256, 0, stream>>>(bufX, ln1_g + l * 512, ln1_b + l * 512);
    for (int rc = 0; rc < 8; ++rc) {
      const long r0 = (long)rc * 6400;
      gemm_kernel<<<dim3(16, 50), 256, 0, stream>>>(
          bufX, r0 * 512, 1 << 30, 0L, 512L,
          ff1_w + (long)l * 1048576, 512, ff1_b + l * 2048, nullptr, 1,
          bufT, nullptr, 0L, 1 << 30, 0L, 2048L, 2048, 512, 0, 1);
      gemm_kernel<<<dim3(4, 50), 256, 0, stream>>>(
          bufT, 0L, 1 << 30, 0L, 2048L,
          ff2_w + (long)l * 1048576, 2048, ff2_b + l * 512, nullptr, 1,
          bufX, nullptr, r0 * 512, 1 << 30, 0L, 512L, 512, 2048, 1, 0);
    }
    ln_kernel<<<12800, 256, 0, stream>>>(bufX, ln2_g + l * 512, ln2_b + l * 512);
  }

  // P[t*100+v, :] = h[t][v] @ att1_w[:, :512]^T   (bf16)
  gemm_kernel<<<dim3(1, 400), 256, 0, stream>>>(
      bufX, 0L, 100, 512L, 262144L, att1_w, 768, nullptr, nullptr, 1,
      nullptr, PbB, 0L, 1 << 30, 0L, 128L, 128, 512, 0, 0);
  // G[t*100+v, :] = h[t][v] @ lstm_wih^T  (bf16)
  gemm_kernel<<<dim3(8, 400), 256, 0, stream>>>(
      bufX, 0L, 100, 512L, 262144L, lstm_wih, 512, nullptr, nullptr, 1,
      nullptr, GbB, 0L, 1 << 30, 0L, 1024L, 1024, 512, 0, 0);

  init_kernel<<<1, 256, 0, stream>>>(s_h_g, a2_g, c_g, cnt);
  decoder_kernel<<<DEC_NB, 256, 0, stream>>>(
      bufX, PbB, GbB, att1_w, att1_b, att2_w,
      lstm_whh, lstm_bih, lstm_bhh, fc1_w, fc1_b, fc2_w, fc2_b,
      s_h_g, a2_g, c_g, cnt, (float*)d_out);
}

// Round 3
// 7881.009 us; speedup vs baseline: 2.2876x; 2.2876x over previous
//
#include <hip/hip_runtime.h>
#include <hip/hip_bf16.h>

// Model dims: Tx=512 V=100 D=64 DM=512 NH=8 DFF=2048 NL=2 H=256 DATT=128 FCH=256 OUT=2

typedef __attribute__((ext_vector_type(8))) short short8;
typedef __attribute__((ext_vector_type(4))) float f32x4;

__device__ __forceinline__ int jglob_of(int e0, int jl) { return ((jl >> 4) << 8) + e0 + (jl & 15); }
__device__ __forceinline__ float blo(unsigned u) { return __uint_as_float(u << 16); }
__device__ __forceinline__ float bhi(unsigned u) { return __uint_as_float(u & 0xffff0000u); }
__device__ __forceinline__ short f2bs(float x) {
  union { __hip_bfloat16 h; short s; } u; u.h = __float2bfloat16(x); return u.s;
}
__device__ __forceinline__ float tanhf_fast(float x) {
  float e = __expf(2.f * x);
  return 1.f - 2.f * __builtin_amdgcn_rcpf(e + 1.f);
}

// ===================== PE table =====================
__global__ __launch_bounds__(256) void pe_kernel(float* __restrict__ pe) {
  int idx = blockIdx.x * 256 + threadIdx.x;
  if (idx >= 100 * 512) return;
  int v = idx >> 9, n = idx & 511;
  float d = expf(-(float)(n & ~1) * (9.2103403719761836f / 512.0f));
  float ang = (float)v * d;
  pe[idx] = (n & 1) ? cosf(ang) : sinf(ang);
}

// ===================== bf16 MFMA tiled GEMM =====================
// out[r,c] = sum_k A[row(r), k] * W[c, k]  (+bias[c] +extra[(r/extraDiv)*N+c]) [relu] [addTo]
// A element offset for row r: aBase + (r/aDiv)*aSA + (r%aDiv)*aSB + k
// out element offset: oBase + (r/oDiv)*oSA + (r%oDiv)*oSB + c*oSC
// M,N multiples of 128, K multiple of 32 (or 64). fp32 in/accum, bf16 MFMA.
__global__ __launch_bounds__(256) void gemm_mfma(
    const float* __restrict__ A, long aBase, int aDiv, long aSA, long aSB,
    const float* __restrict__ W, int ldw,
    const float* __restrict__ bias,
    const float* __restrict__ extra, int extraDiv,
    float* __restrict__ outF, __hip_bfloat16* __restrict__ outB,
    long oBase, int oDiv, long oSA, long oSB, long oSC,
    int N, int K, int addTo, int relu)
{
  __shared__ short As[2][128][40];
  __shared__ short Bs[2][128][40];
  const int tid = threadIdx.x;
  const int rT = blockIdx.y * 128, nT = blockIdx.x * 128;
  const int wave = tid >> 6, lane = tid & 63;
  const int wr = wave >> 1, wc = wave & 1;
  const int lrow = lane & 15, lkg = lane >> 4;
  const int srow = tid >> 1, shf = tid & 1;

  const long arow = aBase + (long)((rT + srow) / aDiv) * aSA + (long)((rT + srow) % aDiv) * aSB + shf * 16;
  const long brow = (long)(nT + srow) * ldw + shf * 16;

  f32x4 acc[4][4];
#pragma unroll
  for (int i = 0; i < 4; ++i)
#pragma unroll
    for (int j = 0; j < 4; ++j) acc[i][j] = (f32x4){0.f, 0.f, 0.f, 0.f};

  float4 ra[4], rb[4];
#define LOADT(K0) do { \
    const float* _pa = A + arow + (K0); \
    ra[0] = *(const float4*)(_pa); ra[1] = *(const float4*)(_pa + 4); \
    ra[2] = *(const float4*)(_pa + 8); ra[3] = *(const float4*)(_pa + 12); \
    const float* _pb = W + brow + (K0); \
    rb[0] = *(const float4*)(_pb); rb[1] = *(const float4*)(_pb + 4); \
    rb[2] = *(const float4*)(_pb + 8); rb[3] = *(const float4*)(_pb + 12); \
  } while (0)

#define CVST(DST, X, Y) do { \
    short8 _v; \
    _v[0] = f2bs((X).x); _v[1] = f2bs((X).y); _v[2] = f2bs((X).z); _v[3] = f2bs((X).w); \
    _v[4] = f2bs((Y).x); _v[5] = f2bs((Y).y); _v[6] = f2bs((Y).z); _v[7] = f2bs((Y).w); \
    *(short8*)(DST) = _v; \
  } while (0)

#define STAGE(BUF) do { \
    CVST(&As[BUF][srow][shf * 16],     ra[0], ra[1]); \
    CVST(&As[BUF][srow][shf * 16 + 8], ra[2], ra[3]); \
    CVST(&Bs[BUF][srow][shf * 16],     rb[0], rb[1]); \
    CVST(&Bs[BUF][srow][shf * 16 + 8], rb[2], rb[3]); \
  } while (0)

  LOADT(0);
  STAGE(0);
  __syncthreads();

  int cur = 0;
  for (int k0 = 0; k0 < K; k0 += 32) {
    const bool nlast = (k0 + 32 < K);
    if (nlast) LOADT(k0 + 32);
    short8 af[4], bfv[4];
#pragma unroll
    for (int f = 0; f < 4; ++f)
      af[f] = *(const short8*)&As[cur][wr * 64 + f * 16 + lrow][lkg * 8];
#pragma unroll
    for (int f = 0; f < 4; ++f)
      bfv[f] = *(const short8*)&Bs[cur][wc * 64 + f * 16 + lrow][lkg * 8];
#pragma unroll
    for (int fm = 0; fm < 4; ++fm)
#pragma unroll
      for (int fn = 0; fn < 4; ++fn)
        acc[fm][fn] = __builtin_amdgcn_mfma_f32_16x16x32_bf16(af[fm], bfv[fn], acc[fm][fn], 0, 0, 0);
    if (nlast) STAGE(cur ^ 1);
    __syncthreads();
    cur ^= 1;
  }

  float bias_v[4];
#pragma unroll
  for (int fn = 0; fn < 4; ++fn)
    bias_v[fn] = bias ? bias[nT + wc * 64 + fn * 16 + lrow] : 0.f;

#pragma unroll
  for (int fm = 0; fm < 4; ++fm) {
#pragma unroll
    for (int r = 0; r < 4; ++r) {
      const int grow = rT + wr * 64 + fm * 16 + lkg * 4 + r;
      const long obase_r = oBase + (long)(grow / oDiv) * oSA + (long)(grow % oDiv) * oSB;
      const long exrow = (long)(grow / extraDiv) * N;
#pragma unroll
      for (int fn = 0; fn < 4; ++fn) {
        const int gcol = nT + wc * 64 + fn * 16 + lrow;
        float v = acc[fm][fn][r] + bias_v[fn];
        if (extra) v += extra[exrow + gcol];
        if (relu) v = fmaxf(v, 0.f);
        const long o = obase_r + (long)gcol * oSC;
        if (outF) { if (addTo) v += outF[o]; outF[o] = v; }
        else outB[o] = __float2bfloat16(v);
      }
    }
  }
#undef LOADT
#undef CVST
#undef STAGE
}

// ===================== attention (per (head, chunk-local b) block) =====================
__global__ __launch_bounds__(256) void attn_kernel(
    const float* __restrict__ qkv, float* __restrict__ outY)
{
  __shared__ float q_s[100][68];
  __shared__ float k_s[100][68];
  __shared__ float v_s[100][68];
  __shared__ float S_s[100][104];
  __shared__ float rs_s[100];
  const int h = blockIdx.x, bl = blockIdx.y, tid = threadIdx.x;

  for (int idx = tid; idx < 100 * 64; idx += 256) {
    int vv = idx >> 6, d = idx & 63;
    long base = ((long)(vv * 64 + bl)) * 1536 + h * 64 + d;
    q_s[vv][d] = qkv[base];
    k_s[vv][d] = qkv[base + 512];
    v_s[vv][d] = qkv[base + 1024];
  }
  __syncthreads();

  const int ty = tid >> 4, tx = tid & 15;
  for (int i0 = 0; i0 < 128; i0 += 64) {
    for (int j0 = 0; j0 < 128; j0 += 64) {
      float acc[4][4];
#pragma unroll
      for (int r = 0; r < 4; ++r)
#pragma unroll
        for (int c = 0; c < 4; ++c) acc[r][c] = 0.f;
      for (int d = 0; d < 64; d += 4) {
        float4 qv[4], kv[4];
#pragma unroll
        for (int r = 0; r < 4; ++r) {
          int ii = i0 + ty * 4 + r; ii = (ii < 100) ? ii : 99;
          qv[r] = *(const float4*)&q_s[ii][d];
        }
#pragma unroll
        for (int c = 0; c < 4; ++c) {
          int jj = j0 + tx * 4 + c; jj = (jj < 100) ? jj : 99;
          kv[c] = *(const float4*)&k_s[jj][d];
        }
#pragma unroll
        for (int r = 0; r < 4; ++r)
#pragma unroll
          for (int c = 0; c < 4; ++c)
            acc[r][c] += qv[r].x * kv[c].x + qv[r].y * kv[c].y + qv[r].z * kv[c].z + qv[r].w * kv[c].w;
      }
#pragma unroll
      for (int r = 0; r < 4; ++r)
#pragma unroll
        for (int c = 0; c < 4; ++c) {
          int ii = i0 + ty * 4 + r, jj = j0 + tx * 4 + c;
          if (ii < 100 && jj < 100) S_s[ii][jj] = acc[r][c] * 0.125f;
        }
    }
  }
  __syncthreads();
  if (tid < 100) {
    float m = -1e30f;
    for (int j = 0; j < 100; ++j) m = fmaxf(m, S_s[tid][j]);
    float s = 0.f;
    for (int j = 0; j < 100; ++j) { float e = __expf(S_s[tid][j] - m); S_s[tid][j] = e; s += e; }
    rs_s[tid] = 1.f / s;
  }
  __syncthreads();
  for (int i0 = 0; i0 < 128; i0 += 64) {
    float acc[4][4];
#pragma unroll
    for (int r = 0; r < 4; ++r)
#pragma unroll
      for (int c = 0; c < 4; ++c) acc[r][c] = 0.f;
    for (int j = 0; j < 100; ++j) {
      float av[4];
#pragma unroll
      for (int r = 0; r < 4; ++r) {
        int ii = i0 + ty * 4 + r; ii = (ii < 100) ? ii : 99;
        av[r] = S_s[ii][j];
      }
      const float4 vv4 = *(const float4*)&v_s[j][tx * 4];
#pragma unroll
      for (int r = 0; r < 4; ++r) {
        acc[r][0] += av[r] * vv4.x; acc[r][1] += av[r] * vv4.y;
        acc[r][2] += av[r] * vv4.z; acc[r][3] += av[r] * vv4.w;
      }
    }
#pragma unroll
    for (int r = 0; r < 4; ++r) {
      int ii = i0 + ty * 4 + r;
      if (ii < 100) {
        float inv = rs_s[ii];
        float4 o; o.x = acc[r][0] * inv; o.y = acc[r][1] * inv; o.z = acc[r][2] * inv; o.w = acc[r][3] * inv;
        *(float4*)(outY + ((long)ii * 64 + bl) * 512 + h * 64 + tx * 4) = o;
      }
    }
  }
}

// ===================== layernorm =====================
__global__ __launch_bounds__(256) void ln_kernel(float* __restrict__ X,
    const float* __restrict__ g, const float* __restrict__ b)
{
  const int row = blockIdx.x * 4 + (threadIdx.x >> 6);
  const int lane = threadIdx.x & 63;
  float* x = X + (long)row * 512;
  float v[8]; float s = 0.f, sq = 0.f;
#pragma unroll
  for (int i = 0; i < 8; ++i) { v[i] = x[lane + i * 64]; s += v[i]; sq += v[i] * v[i]; }
#pragma unroll
  for (int off = 32; off; off >>= 1) { s += __shfl_xor(s, off, 64); sq += __shfl_xor(sq, off, 64); }
  const float mean = s * (1.f / 512.f);
  const float var = sq * (1.f / 512.f) - mean * mean;
  const float inv = rsqrtf(var + 1e-5f);
#pragma unroll
  for (int i = 0; i < 8; ++i) {
    int c = lane + i * 64;
    x[c] = (v[i] - mean) * inv * g[c] + b[c];
  }
}

// ===================== decoder init =====================
__global__ void init_kernel(float* s_h_slots, int* flags, float* c_g) {
  int t = threadIdx.x;
  s_h_slots[t] = 0.f; s_h_slots[256 + t] = 0.f;
  c_g[t] = 0.f; c_g[256 + t] = 0.f;
  if (t < 16) flags[t] = 0;
}

// ===================== decoder: 512-step attention-LSTM scan =====================
// 16 persistent blocks; ONE flag-based sync per step. Block i owns LSTM elements
// e in [i*16, i*16+16) -> gate rows {e, 256+e, 512+e, 768+e}. Softmax computed
// redundantly per block from register-prefetched P; G prefetched [t][j][v].
#define DEC_NB 16

__global__ __launch_bounds__(256, 1) void decoder_kernel(
    const float* __restrict__ X,            // [V*Tx, 512]
    const __hip_bfloat16* __restrict__ Pb,  // [512][100][128]
    const __hip_bfloat16* __restrict__ Gb,  // [512][1024][100]
    const float* __restrict__ att1_w, const float* __restrict__ att1_b,
    const float* __restrict__ att2_w,
    const float* __restrict__ whh,
    const float* __restrict__ bih, const float* __restrict__ bhh,
    const float* __restrict__ fc1_w, const float* __restrict__ fc1_b,
    const float* __restrict__ fc2_w, const float* __restrict__ fc2_b,
    float* s_h_slots, int* flags, float* c_g,
    float* __restrict__ out)
{
  const int tid = threadIdx.x;
  const int blk = blockIdx.x;
  const int e0 = blk * 16;

  __shared__ __align__(16) float Whh_s[64][260];
  __shared__ __align__(16) unsigned short W1b_s[128][264];
  __shared__ __align__(16) float s_h_s[256];
  __shared__ float w2_s[128], ub_s[128], bsum_s[64];
  __shared__ float u_s[128], sc_s[16];
  __shared__ float a2_s[104];
  __shared__ float red_s[256];
  __shared__ float gates_s[64];
  __shared__ float red4_s[4];
  __shared__ float fcin_s[768];
  __shared__ float fca_s[256];

  // one-time LDS staging
  for (int idx = tid; idx < 64 * 256; idx += 256) {
    int jl = idx >> 8, k = idx & 255;
    Whh_s[jl][k] = whh[(long)jglob_of(e0, jl) * 256 + k];
  }
  for (int idx = tid; idx < 128 * 256; idx += 256) {
    int j = idx >> 8, k = idx & 255;
    union { __hip_bfloat16 h; unsigned short u; } cv;
    cv.h = __float2bfloat16(att1_w[(long)j * 768 + 512 + k]);
    W1b_s[j][k] = cv.u;
  }
  if (tid < 128) { w2_s[tid] = att2_w[tid]; ub_s[tid] = att1_b[tid]; }
  if (tid < 64) {
    int jg = jglob_of(e0, tid);
    bsum_s[tid] = bih[jg] + bhh[jg];
  }
  if (tid < 16) sc_s[tid] = 0.f;
  if (tid < 4) a2_s[100 + tid] = 0.f;

  // per-thread constants
  const int pv = tid >> 1, ppart = tid & 1;
  const int pvv = (pv < 100) ? pv : 99;
  const int gjl = tid >> 2, gq = tid & 3;
  const long gRowOff = (long)jglob_of(e0, gjl) * 100 + gq * 26;

  unsigned PC[32];
  unsigned GC[13];

#define PREFETCH(T1) do { \
    const uint4* _pp = (const uint4*)Pb + ((((long)(T1) * 100 + pvv) * 128 + ppart * 64) >> 3); \
    _Pragma("unroll") \
    for (int _i = 0; _i < 8; ++_i) { \
      uint4 _t = _pp[_i]; \
      PC[4*_i] = _t.x; PC[4*_i+1] = _t.y; PC[4*_i+2] = _t.z; PC[4*_i+3] = _t.w; \
    } \
    const unsigned* _gp = (const unsigned*)(Gb + (long)(T1) * 102400 + gRowOff); \
    _Pragma("unroll") \
    for (int _i = 0; _i < 13; ++_i) GC[_i] = _gp[_i]; \
  } while (0)

  PREFETCH(0);
  __syncthreads();

  for (int t = 0; t < 512; ++t) {
    // ---- A: load s_h(t-1) ----
    const int rdS = ((t & 1) ^ 1) << 8;
    float shv = __hip_atomic_load(&s_h_slots[rdS + tid], __ATOMIC_RELAXED, __HIP_MEMORY_SCOPE_AGENT);
    s_h_s[tid] = shv;
    __syncthreads();

    // ---- B: u = W1b . s_h + b ; hh = Whh_rows . s_h ----
    {
      const int j = tid >> 1, hf = tid & 1;
      const unsigned short* wrow = &W1b_s[j][hf * 128];
      float a = 0.f;
#pragma unroll
      for (int i = 0; i < 16; ++i) {
        uint4 wv = *(const uint4*)(wrow + 8 * i);
        const float4 s0 = *(const float4*)&s_h_s[hf * 128 + 8 * i];
        const float4 s1 = *(const float4*)&s_h_s[hf * 128 + 8 * i + 4];
        a += blo(wv.x) * s0.x + bhi(wv.x) * s0.y + blo(wv.y) * s0.z + bhi(wv.y) * s0.w
           + blo(wv.z) * s1.x + bhi(wv.z) * s1.y + blo(wv.w) * s1.z + bhi(wv.w) * s1.w;
      }
      a += __shfl_xor(a, 1, 64);
      if (hf == 0) u_s[j] = a + ub_s[j];
    }
    float hhv;
    {
      const float* wr_ = &Whh_s[gjl][gq * 64];
      float a = 0.f;
#pragma unroll
      for (int i = 0; i < 16; ++i) {
        const float4 w4 = *(const float4*)(wr_ + 4 * i);
        const float4 s4 = *(const float4*)&s_h_s[gq * 64 + 4 * i];
        a += w4.x * s4.x + w4.y * s4.y + w4.z * s4.z + w4.w * s4.w;
      }
      a += __shfl_xor(a, 1, 64);
      a += __shfl_xor(a, 2, 64);
      hhv = a;   // valid where gq==0
    }
    __syncthreads();

    // ---- C: a2[v] = sum_j tanh(P + u) * w2 ----
    {
      float val = 0.f;
#pragma unroll
      for (int jj = 0; jj < 64; ++jj) {
        unsigned u = PC[jj >> 1];
        float pf = (jj & 1) ? bhi(u) : blo(u);
        int col = ppart * 64 + jj;
        val += tanhf_fast(pf + u_s[col]) * w2_s[col];
      }
      val += __shfl_xor(val, 1, 64);
      if (ppart == 0 && pv < 100) a2_s[pv] = val;
    }
    __syncthreads();

    // ---- D: softmax over 100 (wave 0 only) ----
    if (tid < 64) {
      float x0 = a2_s[tid];
      float x1 = (tid + 64 < 100) ? a2_s[tid + 64] : -3.0e38f;
      float m = fmaxf(x0, x1);
#pragma unroll
      for (int off = 32; off; off >>= 1) m = fmaxf(m, __shfl_xor(m, off, 64));
      float ev0 = __expf(x0 - m);
      float ev1 = (tid + 64 < 100) ? __expf(x1 - m) : 0.f;
      float s = ev0 + ev1;
#pragma unroll
      for (int off = 32; off; off >>= 1) s += __shfl_xor(s, off, 64);
      const float inv = 1.f / (s + 1e-15f);
      a2_s[tid] = ev0 * inv;
      if (tid + 64 < 100) a2_s[tid + 64] = ev1 * inv;
    }
    __syncthreads();

    // ---- E: gates_ih + hh + bias ----
    {
      float p = 0.f;
#pragma unroll
      for (int i = 0; i < 13; ++i) {
        unsigned u = GC[i];
        p += a2_s[gq * 26 + 2 * i] * blo(u);
        p += a2_s[gq * 26 + 2 * i + 1] * bhi(u);
      }
      p += __shfl_xor(p, 1, 64);
      p += __shfl_xor(p, 2, 64);
      if (gq == 0) gates_s[gjl] = p + hhv + bsum_s[gjl];
    }
    __syncthreads();

    // ---- F: LSTM update (t<511) or final c (t==511) ----
    if (t < 511) {
      if (tid < 16) {
        const float ig = gates_s[tid], fg = gates_s[16 + tid];
        const float gg = gates_s[32 + tid], og = gates_s[48 + tid];
        const float si = 1.f / (1.f + __expf(-ig));
        const float sf = 1.f / (1.f + __expf(-fg));
        const float so = 1.f / (1.f + __expf(-og));
        const float sc = sf * sc_s[tid] + si * tanhf(gg);
        sc_s[tid] = sc;
        const float sh = so * tanhf(sc);
        __hip_atomic_store(&s_h_slots[((t & 1) << 8) + e0 + tid], sh,
                           __ATOMIC_RELAXED, __HIP_MEMORY_SCOPE_AGENT);
      }
      __syncthreads();
    } else {
      const int dl = tid & 31, vs = tid >> 5;
      const int v0 = vs * 13, v1 = (v0 + 13 < 100) ? v0 + 13 : 100;
      float accc = 0.f;
      for (int v = v0; v < v1; ++v)
        accc += a2_s[v] * X[((long)(v * 512 + 511)) * 512 + blk * 32 + dl];
      red_s[tid] = accc;
      __syncthreads();
      if (tid < 32) {
        float cc = 0.f;
#pragma unroll
        for (int s = 0; s < 8; ++s) cc += red_s[s * 32 + tid];
        __hip_atomic_store(&c_g[blk * 32 + tid], cc, __ATOMIC_RELAXED, __HIP_MEMORY_SCOPE_AGENT);
      }
      __syncthreads();
    }

    // ---- G: release flag, prefetch t+1, poll ----
    if (tid == 0)
      __hip_atomic_store(&flags[blk], t + 1, __ATOMIC_RELEASE, __HIP_MEMORY_SCOPE_AGENT);
    if (t + 1 < 512) PREFETCH(t + 1);
    if (tid < DEC_NB) {
      while (__hip_atomic_load(&flags[tid], __ATOMIC_ACQUIRE, __HIP_MEMORY_SCOPE_AGENT) < t + 1)
        __builtin_amdgcn_s_sleep(1);
    }
    __syncthreads();
  }

  // ---- fc head (block 0). s_h(510) lives in slot 0. ----
  if (blk == 0) {
    fcin_s[tid]       = __hip_atomic_load(&c_g[tid],        __ATOMIC_RELAXED, __HIP_MEMORY_SCOPE_AGENT);
    fcin_s[256 + tid] = __hip_atomic_load(&c_g[256 + tid],  __ATOMIC_RELAXED, __HIP_MEMORY_SCOPE_AGENT);
    fcin_s[512 + tid] = __hip_atomic_load(&s_h_slots[tid],  __ATOMIC_RELAXED, __HIP_MEMORY_SCOPE_AGENT);
    __syncthreads();
    float acc = fc1_b[tid];
    for (int k = 0; k < 768; ++k) acc += fc1_w[(long)tid * 768 + k] * fcin_s[k];
    fca_s[tid] = fmaxf(acc, 0.f);
    __syncthreads();
    if (tid < 128) {
      const int r = tid >> 6, k0 = tid & 63;
      float a = 0.f;
#pragma unroll
      for (int s = 0; s < 4; ++s) a += fc2_w[r * 256 + k0 + s * 64] * fca_s[k0 + s * 64];
#pragma unroll
      for (int off = 32; off; off >>= 1) a += __shfl_xor(a, off, 64);
      if (k0 == 0) red4_s[r] = a + fc2_b[r];
    }
    __syncthreads();
    if (tid == 0) {
      const float l0 = red4_s[0], l1 = red4_s[1];
      const float m = fmaxf(l0, l1);
      const float ls = logf(__expf(l0 - m) + __expf(l1 - m));
      out[0] = l0 - m - ls;
      out[1] = l1 - m - ls;
    }
  }
#undef PREFETCH
}

// ===================== host launch =====================
extern "C" void kernel_launch(void* const* d_in, const int* in_sizes, int n_in,
                              void* d_out, int out_size, void* d_ws, size_t ws_size,
                              hipStream_t stream) {
  const float* x_data  = (const float*)d_in[0];
  const float* feat_w  = (const float*)d_in[1];
  const float* feat_b  = (const float*)d_in[2];
  const float* in_w    = (const float*)d_in[3];
  const float* in_b    = (const float*)d_in[4];
  const float* out_w   = (const float*)d_in[5];
  const float* out_b   = (const float*)d_in[6];
  const float* ff1_w   = (const float*)d_in[7];
  const float* ff1_b   = (const float*)d_in[8];
  const float* ff2_w   = (const float*)d_in[9];
  const float* ff2_b   = (const float*)d_in[10];
  const float* ln1_g   = (const float*)d_in[11];
  const float* ln1_b   = (const float*)d_in[12];
  const float* ln2_g   = (const float*)d_in[13];
  const float* ln2_b   = (const float*)d_in[14];
  const float* att1_w  = (const float*)d_in[15];
  const float* att1_b  = (const float*)d_in[16];
  const float* att2_w  = (const float*)d_in[17];
  const float* lstm_wih = (const float*)d_in[19];
  const float* lstm_whh = (const float*)d_in[20];
  const float* lstm_bih = (const float*)d_in[21];
  const float* lstm_bhh = (const float*)d_in[22];
  const float* fc1_w   = (const float*)d_in[23];
  const float* fc1_b   = (const float*)d_in[24];
  const float* fc2_w   = (const float*)d_in[25];
  const float* fc2_b   = (const float*)d_in[26];

  float* ws   = (float*)d_ws;
  float* bufX = ws;                                        // [51200, 512]
  float* R    = bufX + 26214400;                           // overlay region
  float* bufT = R;                                         // qkv chunk / FF chunk
  float* bufY = R + 13107200;                              // ctx chunk
  __hip_bfloat16* PbB = (__hip_bfloat16*)R;                // [512][100][128] bf16
  __hip_bfloat16* GbB = (__hip_bfloat16*)(R + 3276800);    // [512][1024][100] bf16
  float* pe    = R + 29491200;
  float* s_h_slots = pe + 51200;                           // [2][256]
  int*   flags = (int*)(s_h_slots + 512);                  // [16]
  float* c_g   = (float*)(flags + 16);                     // [512]

  pe_kernel<<<200, 256, 0, stream>>>(pe);

  // feature map + PE
  gemm_mfma<<<dim3(4, 400), 256, 0, stream>>>(
      x_data, 0L, 512, 64L, 6400L, feat_w, 64, feat_b, pe, 512,
      bufX, nullptr, 0L, 1 << 30, 0L, 512L, 1L, 512, 64, 0, 0);

  for (int l = 0; l < 2; ++l) {
    for (int c = 0; c < 8; ++c) {
      const long b0 = c * 64;
      gemm_mfma<<<dim3(12, 50), 256, 0, stream>>>(
          bufX, b0 * 512, 64, 262144L, 512L,
          in_w + (long)l * 786432, 512, in_b + l * 1536, nullptr, 1,
          bufT, nullptr, 0L, 1 << 30, 0L, 1536L, 1L, 1536, 512, 0, 0);
      attn_kernel<<<dim3(8, 64), 256, 0, stream>>>(bufT, bufY);
      gemm_mfma<<<dim3(4, 50), 256, 0, stream>>>(
          bufY, 0L, 1 << 30, 0L, 512L,
          out_w + (long)l * 262144, 512, out_b + l * 512, nullptr, 1,
          bufX, nullptr, b0 * 512, 64, 262144L, 512L, 1L, 512, 512, 1, 0);
    }
    ln_kernel<<<12800, 256, 0, stream>>>(bufX, ln1_g + l * 512, ln1_b + l * 512);
    for (int rc = 0; rc < 8; ++rc) {
      const long r0 = (long)rc * 6400;
      gemm_mfma<<<dim3(16, 50), 256, 0, stream>>>(
          bufX, r0 * 512, 1 << 30, 0L, 512L,
          ff1_w + (long)l * 1048576, 512, ff1_b + l * 2048, nullptr, 1,
          bufT, nullptr, 0L, 1 << 30, 0L, 2048L, 1L, 2048, 512, 0, 1);
      gemm_mfma<<<dim3(4, 50), 256, 0, stream>>>(
          bufT, 0L, 1 << 30, 0L, 2048L,
          ff2_w + (long)l * 1048576, 2048, ff2_b + l * 512, nullptr, 1,
          bufX, nullptr, r0 * 512, 1 << 30, 0L, 512L, 1L, 512, 2048, 1, 0);
    }
    ln_kernel<<<12800, 256, 0, stream>>>(bufX, ln2_g + l * 512, ln2_b + l * 512);
  }

  // P[t][v][:] = h[t][v] @ att1_w[:, :512]^T   (bf16)
  gemm_mfma<<<dim3(1, 400), 256, 0, stream>>>(
      bufX, 0L, 100, 512L, 262144L, att1_w, 768, nullptr, nullptr, 1,
      nullptr, PbB, 0L, 1 << 30, 0L, 128L, 1L, 128, 512, 0, 0);
  // G[t][j][v] = (h[t][v] @ lstm_wih^T)[j]  (bf16, transposed store)
  gemm_mfma<<<dim3(8, 400), 256, 0, stream>>>(
      bufX, 0L, 100, 512L, 262144L, lstm_wih, 512, nullptr, nullptr, 1,
      nullptr, GbB, 0L, 100, 102400L, 1L, 100L, 1024, 512, 0, 0);

  init_kernel<<<1, 256, 0, stream>>>(s_h_slots, flags, c_g);
  decoder_kernel<<<DEC_NB, 256, 0, stream>>>(
      bufX, PbB, GbB, att1_w, att1_b, att2_w,
      lstm_whh, lstm_bih, lstm_bhh, fc1_w, fc1_b, fc2_w, fc2_b,
      s_h_slots, flags, c_g, (float*)d_out);
}

// Round 4
// 6302.670 us; speedup vs baseline: 2.8604x; 1.2504x over previous
//
#include <hip/hip_runtime.h>
#include <hip/hip_bf16.h>

// Model dims: Tx=512 V=100 D=64 DM=512 NH=8 DFF=2048 NL=2 H=256 DATT=128 FCH=256 OUT=2

typedef __attribute__((ext_vector_type(8))) short short8;
typedef __attribute__((ext_vector_type(4))) float f32x4;

__device__ __forceinline__ int jglob_of(int e0, int jl) { return ((jl >> 4) << 8) + e0 + (jl & 15); }
__device__ __forceinline__ float blo(unsigned u) { return __uint_as_float(u << 16); }
__device__ __forceinline__ float bhi(unsigned u) { return __uint_as_float(u & 0xffff0000u); }
__device__ __forceinline__ short f2bs(float x) {
  union { __hip_bfloat16 h; short s; } u; u.h = __float2bfloat16(x); return u.s;
}
__device__ __forceinline__ float tanhf_fast(float x) {
  float e = __expf(2.f * x);
  return 1.f - 2.f * __builtin_amdgcn_rcpf(e + 1.f);
}

#define GLL16(GSRC, LDST) \
  __builtin_amdgcn_global_load_lds( \
      (const __attribute__((address_space(1))) unsigned int*)(GSRC), \
      (__attribute__((address_space(3))) unsigned int*)(LDST), 16, 0, 0)

// ===================== PE table =====================
__global__ __launch_bounds__(256) void pe_kernel(float* __restrict__ pe) {
  int idx = blockIdx.x * 256 + threadIdx.x;
  if (idx >= 100 * 512) return;
  int v = idx >> 9, n = idx & 511;
  float d = expf(-(float)(n & ~1) * (9.2103403719761836f / 512.0f));
  float ang = (float)v * d;
  pe[idx] = (n & 1) ? cosf(ang) : sinf(ang);
}

// ===================== fp32 -> bf16 convert =====================
__global__ __launch_bounds__(256) void cvt_kernel(const float* __restrict__ src,
                                                  __hip_bfloat16* __restrict__ dst, int n) {
  int i = blockIdx.x * 256 + threadIdx.x;
  if (i < n) dst[i] = __float2bfloat16(src[i]);
}

// ===================== bf16-input MFMA GEMM (m97-style) =====================
// out[r,c] = sum_k A[row(r),k] * W[c,k] (+bias[c]) [relu] [addTo]
// A element offset: aBase + (r/aDiv)*aSA + (r%aDiv)*aSB + k   (bf16 elements)
// out element offset: oBase + (r/oDiv)*oSA + (r%oDiv)*oSB + c
// M,N multiples of 128; K multiple of 64. global_load_lds w16, pre-swizzled src.
__global__ __launch_bounds__(256) void gemm_bf16(
    const __hip_bfloat16* __restrict__ A, long aBase, int aDiv, long aSA, long aSB,
    const __hip_bfloat16* __restrict__ W, int ldw,
    const float* __restrict__ bias,
    float* __restrict__ outF, __hip_bfloat16* __restrict__ outB,
    long oBase, int oDiv, long oSA, long oSB,
    int K, int addTo, int relu)
{
  __shared__ __hip_bfloat16 As[128 * 64];
  __shared__ __hip_bfloat16 Bs[128 * 64];
  const int tid = threadIdx.x;
  const int rT = blockIdx.y * 128, nT = blockIdx.x * 128;
  const int wave = tid >> 6, lane = tid & 63;
  const int wr = wave >> 1, wc = wave & 1;
  const int lrow = lane & 15, lkg = lane >> 4;

  // staging source addresses (pre-swizzled chunk within row: sc = (lane&7)^(lane>>3))
  long asrc[4], bsrc[4];
  const int sc8 = ((lane & 7) ^ (lane >> 3)) * 8;
#pragma unroll
  for (int i = 0; i < 4; ++i) {
    const int chunk = wave * 4 + i;
    const int row = chunk * 8 + (lane >> 3);
    const int gr = rT + row;
    asrc[i] = aBase + (long)(gr / aDiv) * aSA + (long)(gr % aDiv) * aSB + sc8;
    bsrc[i] = (long)(nT + row) * ldw + sc8;
  }

  f32x4 acc[4][4];
#pragma unroll
  for (int i = 0; i < 4; ++i)
#pragma unroll
    for (int j = 0; j < 4; ++j) acc[i][j] = (f32x4){0.f, 0.f, 0.f, 0.f};

  for (int k0 = 0; k0 < K; k0 += 64) {
#pragma unroll
    for (int i = 0; i < 4; ++i) {
      const int chunk = wave * 4 + i;
      GLL16(A + asrc[i] + k0, &As[chunk * 512]);
      GLL16(W + bsrc[i] + k0, &Bs[chunk * 512]);
    }
    __syncthreads();
#pragma unroll
    for (int ks = 0; ks < 2; ++ks) {
      short8 af[4], bfv[4];
#pragma unroll
      for (int f = 0; f < 4; ++f) {
        const int Ra = wr * 64 + f * 16 + lrow;
        af[f] = *(const short8*)&As[Ra * 64 + (((ks * 4 + lkg) ^ (Ra & 7)) * 8)];
        const int Rb = wc * 64 + f * 16 + lrow;
        bfv[f] = *(const short8*)&Bs[Rb * 64 + (((ks * 4 + lkg) ^ (Rb & 7)) * 8)];
      }
#pragma unroll
      for (int fm = 0; fm < 4; ++fm)
#pragma unroll
        for (int fn = 0; fn < 4; ++fn)
          acc[fm][fn] = __builtin_amdgcn_mfma_f32_16x16x32_bf16(af[fm], bfv[fn], acc[fm][fn], 0, 0, 0);
    }
    __syncthreads();
  }

  float bias_v[4];
#pragma unroll
  for (int fn = 0; fn < 4; ++fn)
    bias_v[fn] = bias ? bias[nT + wc * 64 + fn * 16 + lrow] : 0.f;

#pragma unroll
  for (int fm = 0; fm < 4; ++fm) {
#pragma unroll
    for (int r = 0; r < 4; ++r) {
      const int grow = rT + wr * 64 + fm * 16 + lkg * 4 + r;
      const long obase_r = oBase + (long)(grow / oDiv) * oSA + (long)(grow % oDiv) * oSB;
#pragma unroll
      for (int fn = 0; fn < 4; ++fn) {
        const int gcol = nT + wc * 64 + fn * 16 + lrow;
        float v = acc[fm][fn][r] + bias_v[fn];
        if (relu) v = fmaxf(v, 0.f);
        const long o = obase_r + gcol;
        if (outF) { if (addTo) v += outF[o]; outF[o] = v; }
        else outB[o] = __float2bfloat16(v);
      }
    }
  }
}

// ===================== fp32-input MFMA GEMM (feat / P / G) =====================
__global__ __launch_bounds__(256) void gemm_mfma(
    const float* __restrict__ A, long aBase, int aDiv, long aSA, long aSB,
    const float* __restrict__ W, int ldw,
    const float* __restrict__ bias,
    const float* __restrict__ extra, int extraDiv,
    float* __restrict__ outF, __hip_bfloat16* __restrict__ outB,
    __hip_bfloat16* __restrict__ outB2,
    long oBase, int oDiv, long oSA, long oSB, long oSC,
    int N, int K, int addTo, int relu)
{
  __shared__ short As[2][128][40];
  __shared__ short Bs[2][128][40];
  const int tid = threadIdx.x;
  const int rT = blockIdx.y * 128, nT = blockIdx.x * 128;
  const int wave = tid >> 6, lane = tid & 63;
  const int wr = wave >> 1, wc = wave & 1;
  const int lrow = lane & 15, lkg = lane >> 4;
  const int srow = tid >> 1, shf = tid & 1;

  const long arow = aBase + (long)((rT + srow) / aDiv) * aSA + (long)((rT + srow) % aDiv) * aSB + shf * 16;
  const long brow = (long)(nT + srow) * ldw + shf * 16;

  f32x4 acc[4][4];
#pragma unroll
  for (int i = 0; i < 4; ++i)
#pragma unroll
    for (int j = 0; j < 4; ++j) acc[i][j] = (f32x4){0.f, 0.f, 0.f, 0.f};

  float4 ra[4], rb[4];
#define LOADT(K0) do { \
    const float* _pa = A + arow + (K0); \
    ra[0] = *(const float4*)(_pa); ra[1] = *(const float4*)(_pa + 4); \
    ra[2] = *(const float4*)(_pa + 8); ra[3] = *(const float4*)(_pa + 12); \
    const float* _pb = W + brow + (K0); \
    rb[0] = *(const float4*)(_pb); rb[1] = *(const float4*)(_pb + 4); \
    rb[2] = *(const float4*)(_pb + 8); rb[3] = *(const float4*)(_pb + 12); \
  } while (0)

#define CVST(DST, X, Y) do { \
    short8 _v; \
    _v[0] = f2bs((X).x); _v[1] = f2bs((X).y); _v[2] = f2bs((X).z); _v[3] = f2bs((X).w); \
    _v[4] = f2bs((Y).x); _v[5] = f2bs((Y).y); _v[6] = f2bs((Y).z); _v[7] = f2bs((Y).w); \
    *(short8*)(DST) = _v; \
  } while (0)

#define STAGE(BUF) do { \
    CVST(&As[BUF][srow][shf * 16],     ra[0], ra[1]); \
    CVST(&As[BUF][srow][shf * 16 + 8], ra[2], ra[3]); \
    CVST(&Bs[BUF][srow][shf * 16],     rb[0], rb[1]); \
    CVST(&Bs[BUF][srow][shf * 16 + 8], rb[2], rb[3]); \
  } while (0)

  LOADT(0);
  STAGE(0);
  __syncthreads();

  int cur = 0;
  for (int k0 = 0; k0 < K; k0 += 32) {
    const bool nlast = (k0 + 32 < K);
    if (nlast) LOADT(k0 + 32);
    short8 af[4], bfv[4];
#pragma unroll
    for (int f = 0; f < 4; ++f)
      af[f] = *(const short8*)&As[cur][wr * 64 + f * 16 + lrow][lkg * 8];
#pragma unroll
    for (int f = 0; f < 4; ++f)
      bfv[f] = *(const short8*)&Bs[cur][wc * 64 + f * 16 + lrow][lkg * 8];
#pragma unroll
    for (int fm = 0; fm < 4; ++fm)
#pragma unroll
      for (int fn = 0; fn < 4; ++fn)
        acc[fm][fn] = __builtin_amdgcn_mfma_f32_16x16x32_bf16(af[fm], bfv[fn], acc[fm][fn], 0, 0, 0);
    if (nlast) STAGE(cur ^ 1);
    __syncthreads();
    cur ^= 1;
  }

  float bias_v[4];
#pragma unroll
  for (int fn = 0; fn < 4; ++fn)
    bias_v[fn] = bias ? bias[nT + wc * 64 + fn * 16 + lrow] : 0.f;

#pragma unroll
  for (int fm = 0; fm < 4; ++fm) {
#pragma unroll
    for (int r = 0; r < 4; ++r) {
      const int grow = rT + wr * 64 + fm * 16 + lkg * 4 + r;
      const long obase_r = oBase + (long)(grow / oDiv) * oSA + (long)(grow % oDiv) * oSB;
      const long exrow = (long)(grow / extraDiv) * N;
#pragma unroll
      for (int fn = 0; fn < 4; ++fn) {
        const int gcol = nT + wc * 64 + fn * 16 + lrow;
        float v = acc[fm][fn][r] + bias_v[fn];
        if (extra) v += extra[exrow + gcol];
        if (relu) v = fmaxf(v, 0.f);
        const long o = obase_r + (long)gcol * oSC;
        if (outF) { if (addTo) v += outF[o]; outF[o] = v; }
        else outB[o] = __float2bfloat16(v);
        if (outB2) outB2[o] = __float2bfloat16(v);
      }
    }
  }
#undef LOADT
#undef CVST
#undef STAGE
}

// ===================== attention (per (head, chunk-local b) block), bf16 io =====================
__global__ __launch_bounds__(256) void attn_kernel(
    const __hip_bfloat16* __restrict__ qkv, __hip_bfloat16* __restrict__ outY)
{
  __shared__ float q_s[100][68];
  __shared__ float k_s[100][68];
  __shared__ float v_s[100][68];
  __shared__ float S_s[100][104];
  __shared__ float rs_s[100];
  const int h = blockIdx.x, bl = blockIdx.y, tid = threadIdx.x;

  for (int idx = tid; idx < 100 * 64; idx += 256) {
    int vv = idx >> 6, d = idx & 63;
    long base = ((long)(vv * 128 + bl)) * 1536 + h * 64 + d;
    q_s[vv][d] = __bfloat162float(qkv[base]);
    k_s[vv][d] = __bfloat162float(qkv[base + 512]);
    v_s[vv][d] = __bfloat162float(qkv[base + 1024]);
  }
  __syncthreads();

  const int ty = tid >> 4, tx = tid & 15;
  for (int i0 = 0; i0 < 128; i0 += 64) {
    for (int j0 = 0; j0 < 128; j0 += 64) {
      float acc[4][4];
#pragma unroll
      for (int r = 0; r < 4; ++r)
#pragma unroll
        for (int c = 0; c < 4; ++c) acc[r][c] = 0.f;
      for (int d = 0; d < 64; d += 4) {
        float4 qv[4], kv[4];
#pragma unroll
        for (int r = 0; r < 4; ++r) {
          int ii = i0 + ty * 4 + r; ii = (ii < 100) ? ii : 99;
          qv[r] = *(const float4*)&q_s[ii][d];
        }
#pragma unroll
        for (int c = 0; c < 4; ++c) {
          int jj = j0 + tx * 4 + c; jj = (jj < 100) ? jj : 99;
          kv[c] = *(const float4*)&k_s[jj][d];
        }
#pragma unroll
        for (int r = 0; r < 4; ++r)
#pragma unroll
          for (int c = 0; c < 4; ++c)
            acc[r][c] += qv[r].x * kv[c].x + qv[r].y * kv[c].y + qv[r].z * kv[c].z + qv[r].w * kv[c].w;
      }
#pragma unroll
      for (int r = 0; r < 4; ++r)
#pragma unroll
        for (int c = 0; c < 4; ++c) {
          int ii = i0 + ty * 4 + r, jj = j0 + tx * 4 + c;
          if (ii < 100 && jj < 100) S_s[ii][jj] = acc[r][c] * 0.125f;
        }
    }
  }
  __syncthreads();
  if (tid < 100) {
    float m = -1e30f;
    for (int j = 0; j < 100; ++j) m = fmaxf(m, S_s[tid][j]);
    float s = 0.f;
    for (int j = 0; j < 100; ++j) { float e = __expf(S_s[tid][j] - m); S_s[tid][j] = e; s += e; }
    rs_s[tid] = 1.f / s;
  }
  __syncthreads();
  for (int i0 = 0; i0 < 128; i0 += 64) {
    float acc[4][4];
#pragma unroll
    for (int r = 0; r < 4; ++r)
#pragma unroll
      for (int c = 0; c < 4; ++c) acc[r][c] = 0.f;
    for (int j = 0; j < 100; ++j) {
      float av[4];
#pragma unroll
      for (int r = 0; r < 4; ++r) {
        int ii = i0 + ty * 4 + r; ii = (ii < 100) ? ii : 99;
        av[r] = S_s[ii][j];
      }
      const float4 vv4 = *(const float4*)&v_s[j][tx * 4];
#pragma unroll
      for (int r = 0; r < 4; ++r) {
        acc[r][0] += av[r] * vv4.x; acc[r][1] += av[r] * vv4.y;
        acc[r][2] += av[r] * vv4.z; acc[r][3] += av[r] * vv4.w;
      }
    }
#pragma unroll
    for (int r = 0; r < 4; ++r) {
      int ii = i0 + ty * 4 + r;
      if (ii < 100) {
        float inv = rs_s[ii];
        __hip_bfloat16* op = outY + ((long)ii * 128 + bl) * 512 + h * 64 + tx * 4;
        op[0] = __float2bfloat16(acc[r][0] * inv);
        op[1] = __float2bfloat16(acc[r][1] * inv);
        op[2] = __float2bfloat16(acc[r][2] * inv);
        op[3] = __float2bfloat16(acc[r][3] * inv);
      }
    }
  }
}

// ===================== layernorm (in-place + bf16 mirror) =====================
__global__ __launch_bounds__(256) void ln_kernel(float* __restrict__ X,
    __hip_bfloat16* __restrict__ Xb,
    const float* __restrict__ g, const float* __restrict__ b)
{
  const int row = blockIdx.x * 4 + (threadIdx.x >> 6);
  const int lane = threadIdx.x & 63;
  float* x = X + (long)row * 512;
  __hip_bfloat16* xb = Xb + (long)row * 512;
  float v[8]; float s = 0.f, sq = 0.f;
#pragma unroll
  for (int i = 0; i < 8; ++i) { v[i] = x[lane + i * 64]; s += v[i]; sq += v[i] * v[i]; }
#pragma unroll
  for (int off = 32; off; off >>= 1) { s += __shfl_xor(s, off, 64); sq += __shfl_xor(sq, off, 64); }
  const float mean = s * (1.f / 512.f);
  const float var = sq * (1.f / 512.f) - mean * mean;
  const float inv = rsqrtf(var + 1e-5f);
#pragma unroll
  for (int i = 0; i < 8; ++i) {
    int c = lane + i * 64;
    float r = (v[i] - mean) * inv * g[c] + b[c];
    x[c] = r;
    xb[c] = __float2bfloat16(r);
  }
}

// ===================== decoder init =====================
__global__ void init_kernel(float* s_h_slots, int* flags, float* c_g) {
  int t = threadIdx.x;
  s_h_slots[t] = 0.f; s_h_slots[256 + t] = 0.f;
  c_g[t] = 0.f; c_g[256 + t] = 0.f;
  if (t < 16) flags[t] = 0;
}

// ===================== decoder: 512-step attention-LSTM scan =====================
#define DEC_NB 16

__global__ __launch_bounds__(256, 1) void decoder_kernel(
    const float* __restrict__ X,            // [V*Tx, 512]
    const __hip_bfloat16* __restrict__ Pb,  // [512][100][128]
    const __hip_bfloat16* __restrict__ Gb,  // [512][1024][100]
    const float* __restrict__ att1_w, const float* __restrict__ att1_b,
    const float* __restrict__ att2_w,
    const float* __restrict__ whh,
    const float* __restrict__ bih, const float* __restrict__ bhh,
    const float* __restrict__ fc1_w, const float* __restrict__ fc1_b,
    const float* __restrict__ fc2_w, const float* __restrict__ fc2_b,
    float* s_h_slots, int* flags, float* c_g,
    float* __restrict__ out)
{
  const int tid = threadIdx.x;
  const int blk = blockIdx.x;
  const int e0 = blk * 16;

  __shared__ __align__(16) float Whh_s[64][260];
  __shared__ __align__(16) unsigned short W1b_s[128][264];
  __shared__ __align__(16) float s_h_s[256];
  __shared__ float w2_s[128], ub_s[128], bsum_s[64];
  __shared__ float u_s[128], sc_s[16];
  __shared__ float a2_s[104];
  __shared__ float red_s[256];
  __shared__ float gates_s[64];
  __shared__ float red4_s[4];
  __shared__ float fcin_s[768];
  __shared__ float fca_s[256];

  for (int idx = tid; idx < 64 * 256; idx += 256) {
    int jl = idx >> 8, k = idx & 255;
    Whh_s[jl][k] = whh[(long)jglob_of(e0, jl) * 256 + k];
  }
  for (int idx = tid; idx < 128 * 256; idx += 256) {
    int j = idx >> 8, k = idx & 255;
    union { __hip_bfloat16 h; unsigned short u; } cv;
    cv.h = __float2bfloat16(att1_w[(long)j * 768 + 512 + k]);
    W1b_s[j][k] = cv.u;
  }
  if (tid < 128) { w2_s[tid] = att2_w[tid]; ub_s[tid] = att1_b[tid]; }
  if (tid < 64) {
    int jg = jglob_of(e0, tid);
    bsum_s[tid] = bih[jg] + bhh[jg];
  }
  if (tid < 16) sc_s[tid] = 0.f;
  if (tid < 4) a2_s[100 + tid] = 0.f;

  const int pv = tid >> 1, ppart = tid & 1;
  const int pvv = (pv < 100) ? pv : 99;
  const int gjl = tid >> 2, gq = tid & 3;
  const long gRowOff = (long)jglob_of(e0, gjl) * 100 + gq * 26;

  unsigned PC[32];
  unsigned GC[13];

#define PREFETCH(T1) do { \
    const uint4* _pp = (const uint4*)Pb + ((((long)(T1) * 100 + pvv) * 128 + ppart * 64) >> 3); \
    _Pragma("unroll") \
    for (int _i = 0; _i < 8; ++_i) { \
      uint4 _t = _pp[_i]; \
      PC[4*_i] = _t.x; PC[4*_i+1] = _t.y; PC[4*_i+2] = _t.z; PC[4*_i+3] = _t.w; \
    } \
    const unsigned* _gp = (const unsigned*)(Gb + (long)(T1) * 102400 + gRowOff); \
    _Pragma("unroll") \
    for (int _i = 0; _i < 13; ++_i) GC[_i] = _gp[_i]; \
  } while (0)

  PREFETCH(0);
  __syncthreads();

  for (int t = 0; t < 512; ++t) {
    // ---- A: load s_h(t-1) ----
    const int rdS = ((t & 1) ^ 1) << 8;
    float shv = __hip_atomic_load(&s_h_slots[rdS + tid], __ATOMIC_RELAXED, __HIP_MEMORY_SCOPE_AGENT);
    s_h_s[tid] = shv;
    __syncthreads();

    // ---- B: u = W1b . s_h + b ; hh = Whh_rows . s_h ----
    {
      const int j = tid >> 1, hf = tid & 1;
      const unsigned short* wrow = &W1b_s[j][hf * 128];
      float a = 0.f;
#pragma unroll
      for (int i = 0; i < 16; ++i) {
        uint4 wv = *(const uint4*)(wrow + 8 * i);
        const float4 s0 = *(const float4*)&s_h_s[hf * 128 + 8 * i];
        const float4 s1 = *(const float4*)&s_h_s[hf * 128 + 8 * i + 4];
        a += blo(wv.x) * s0.x + bhi(wv.x) * s0.y + blo(wv.y) * s0.z + bhi(wv.y) * s0.w
           + blo(wv.z) * s1.x + bhi(wv.z) * s1.y + blo(wv.w) * s1.z + bhi(wv.w) * s1.w;
      }
      a += __shfl_xor(a, 1, 64);
      if (hf == 0) u_s[j] = a + ub_s[j];
    }
    float hhv;
    {
      const float* wr_ = &Whh_s[gjl][gq * 64];
      float a = 0.f;
#pragma unroll
      for (int i = 0; i < 16; ++i) {
        const float4 w4 = *(const float4*)(wr_ + 4 * i);
        const float4 s4 = *(const float4*)&s_h_s[gq * 64 + 4 * i];
        a += w4.x * s4.x + w4.y * s4.y + w4.z * s4.z + w4.w * s4.w;
      }
      a += __shfl_xor(a, 1, 64);
      a += __shfl_xor(a, 2, 64);
      hhv = a;
    }
    __syncthreads();

    // ---- C: a2[v] = sum_j tanh(P + u) * w2 ----
    {
      float val = 0.f;
#pragma unroll
      for (int jj = 0; jj < 64; ++jj) {
        unsigned u = PC[jj >> 1];
        float pf = (jj & 1) ? bhi(u) : blo(u);
        int col = ppart * 64 + jj;
        val += tanhf_fast(pf + u_s[col]) * w2_s[col];
      }
      val += __shfl_xor(val, 1, 64);
      if (ppart == 0 && pv < 100) a2_s[pv] = val;
    }
    __syncthreads();

    // ---- D: softmax over 100 (wave 0) ----
    if (tid < 64) {
      float x0 = a2_s[tid];
      float x1 = (tid + 64 < 100) ? a2_s[tid + 64] : -3.0e38f;
      float m = fmaxf(x0, x1);
#pragma unroll
      for (int off = 32; off; off >>= 1) m = fmaxf(m, __shfl_xor(m, off, 64));
      float ev0 = __expf(x0 - m);
      float ev1 = (tid + 64 < 100) ? __expf(x1 - m) : 0.f;
      float s = ev0 + ev1;
#pragma unroll
      for (int off = 32; off; off >>= 1) s += __shfl_xor(s, off, 64);
      const float inv = 1.f / (s + 1e-15f);
      a2_s[tid] = ev0 * inv;
      if (tid + 64 < 100) a2_s[tid + 64] = ev1 * inv;
    }
    __syncthreads();

    // ---- E: gates ----
    {
      float p = 0.f;
#pragma unroll
      for (int i = 0; i < 13; ++i) {
        unsigned u = GC[i];
        p += a2_s[gq * 26 + 2 * i] * blo(u);
        p += a2_s[gq * 26 + 2 * i + 1] * bhi(u);
      }
      p += __shfl_xor(p, 1, 64);
      p += __shfl_xor(p, 2, 64);
      if (gq == 0) gates_s[gjl] = p + hhv + bsum_s[gjl];
    }
    __syncthreads();

    // ---- F: LSTM update or final c ----
    if (t < 511) {
      if (tid < 16) {
        const float ig = gates_s[tid], fg = gates_s[16 + tid];
        const float gg = gates_s[32 + tid], og = gates_s[48 + tid];
        const float si = 1.f / (1.f + __expf(-ig));
        const float sf = 1.f / (1.f + __expf(-fg));
        const float so = 1.f / (1.f + __expf(-og));
        const float sc = sf * sc_s[tid] + si * tanhf(gg);
        sc_s[tid] = sc;
        const float sh = so * tanhf(sc);
        __hip_atomic_store(&s_h_slots[((t & 1) << 8) + e0 + tid], sh,
                           __ATOMIC_RELAXED, __HIP_MEMORY_SCOPE_AGENT);
      }
      __syncthreads();
    } else {
      const int dl = tid & 31, vs = tid >> 5;
      const int v0 = vs * 13, v1 = (v0 + 13 < 100) ? v0 + 13 : 100;
      float accc = 0.f;
      for (int v = v0; v < v1; ++v)
        accc += a2_s[v] * X[((long)(v * 512 + 511)) * 512 + blk * 32 + dl];
      red_s[tid] = accc;
      __syncthreads();
      if (tid < 32) {
        float cc = 0.f;
#pragma unroll
        for (int s = 0; s < 8; ++s) cc += red_s[s * 32 + tid];
        __hip_atomic_store(&c_g[blk * 32 + tid], cc, __ATOMIC_RELAXED, __HIP_MEMORY_SCOPE_AGENT);
      }
      __syncthreads();
    }

    // ---- G: release flag, prefetch t+1, relaxed poll, one acquire fence ----
    if (tid == 0)
      __hip_atomic_store(&flags[blk], t + 1, __ATOMIC_RELEASE, __HIP_MEMORY_SCOPE_AGENT);
    if (t + 1 < 512) PREFETCH(t + 1);
    if (tid < DEC_NB) {
      while (__hip_atomic_load(&flags[tid], __ATOMIC_RELAXED, __HIP_MEMORY_SCOPE_AGENT) < t + 1)
        __builtin_amdgcn_s_sleep(1);
    }
    __builtin_amdgcn_fence(__ATOMIC_ACQUIRE, "agent");
    __syncthreads();
  }

  // ---- fc head (block 0). s_h(510) lives in slot 0. ----
  if (blk == 0) {
    fcin_s[tid]       = __hip_atomic_load(&c_g[tid],        __ATOMIC_RELAXED, __HIP_MEMORY_SCOPE_AGENT);
    fcin_s[256 + tid] = __hip_atomic_load(&c_g[256 + tid],  __ATOMIC_RELAXED, __HIP_MEMORY_SCOPE_AGENT);
    fcin_s[512 + tid] = __hip_atomic_load(&s_h_slots[tid],  __ATOMIC_RELAXED, __HIP_MEMORY_SCOPE_AGENT);
    __syncthreads();
    float acc = fc1_b[tid];
    for (int k = 0; k < 768; ++k) acc += fc1_w[(long)tid * 768 + k] * fcin_s[k];
    fca_s[tid] = fmaxf(acc, 0.f);
    __syncthreads();
    if (tid < 128) {
      const int r = tid >> 6, k0 = tid & 63;
      float a = 0.f;
#pragma unroll
      for (int s = 0; s < 4; ++s) a += fc2_w[r * 256 + k0 + s * 64] * fca_s[k0 + s * 64];
#pragma unroll
      for (int off = 32; off; off >>= 1) a += __shfl_xor(a, off, 64);
      if (k0 == 0) red4_s[r] = a + fc2_b[r];
    }
    __syncthreads();
    if (tid == 0) {
      const float l0 = red4_s[0], l1 = red4_s[1];
      const float m = fmaxf(l0, l1);
      const float ls = logf(__expf(l0 - m) + __expf(l1 - m));
      out[0] = l0 - m - ls;
      out[1] = l1 - m - ls;
    }
  }
#undef PREFETCH
}

// ===================== host launch =====================
extern "C" void kernel_launch(void* const* d_in, const int* in_sizes, int n_in,
                              void* d_out, int out_size, void* d_ws, size_t ws_size,
                              hipStream_t stream) {
  const float* x_data  = (const float*)d_in[0];
  const float* feat_w  = (const float*)d_in[1];
  const float* feat_b  = (const float*)d_in[2];
  const float* in_w    = (const float*)d_in[3];
  const float* in_b    = (const float*)d_in[4];
  const float* out_w   = (const float*)d_in[5];
  const float* out_b   = (const float*)d_in[6];
  const float* ff1_w   = (const float*)d_in[7];
  const float* ff1_b   = (const float*)d_in[8];
  const float* ff2_w   = (const float*)d_in[9];
  const float* ff2_b   = (const float*)d_in[10];
  const float* ln1_g   = (const float*)d_in[11];
  const float* ln1_b   = (const float*)d_in[12];
  const float* ln2_g   = (const float*)d_in[13];
  const float* ln2_b   = (const float*)d_in[14];
  const float* att1_w  = (const float*)d_in[15];
  const float* att1_b  = (const float*)d_in[16];
  const float* att2_w  = (const float*)d_in[17];
  const float* lstm_wih = (const float*)d_in[19];
  const float* lstm_whh = (const float*)d_in[20];
  const float* lstm_bih = (const float*)d_in[21];
  const float* lstm_bhh = (const float*)d_in[22];
  const float* fc1_w   = (const float*)d_in[23];
  const float* fc1_b   = (const float*)d_in[24];
  const float* fc2_w   = (const float*)d_in[25];
  const float* fc2_b   = (const float*)d_in[26];

  // ---- workspace layout (same 218 MB footprint as round 3) ----
  float* ws   = (float*)d_ws;
  float* Xf   = ws;                                        // [51200,512] f32
  float* R    = Xf + 26214400;                             // overlay, 29,491,200 f
  // transformer phase:
  __hip_bfloat16* Xb   = (__hip_bfloat16*)R;               // [51200,512] bf16 (13,107,200 f)
  __hip_bfloat16* qkvb = (__hip_bfloat16*)(R + 13107200);  // [12800,1536] bf16 (9,830,400 f)
  __hip_bfloat16* ctxb = (__hip_bfloat16*)(R + 22937600);  // [12800,512] bf16 (3,276,800 f)
  __hip_bfloat16* ffh  = (__hip_bfloat16*)(R + 13107200);  // [12800,2048] bf16 (13,107,200 f)
  __hip_bfloat16* wb   = (__hip_bfloat16*)(R + 26214400);  // weights bf16 (3,145,728 f)
  __hip_bfloat16* in_wb  = wb;                             // 2*786432
  __hip_bfloat16* out_wb = wb + 1572864;                   // 2*262144
  __hip_bfloat16* ff1_wb = out_wb + 524288;                // 2*1048576
  __hip_bfloat16* ff2_wb = ff1_wb + 2097152;               // 2*1048576
  // decoder-precompute phase (overwrites transformer R):
  __hip_bfloat16* PbB = (__hip_bfloat16*)R;                // [512][100][128] bf16
  __hip_bfloat16* GbB = (__hip_bfloat16*)(R + 3276800);    // [512][1024][100] bf16
  float* pe    = R + 29491200;
  float* s_h_slots = pe + 51200;                           // [2][256]
  int*   flags = (int*)(s_h_slots + 512);                  // [16]
  float* c_g   = (float*)(flags + 16);                     // [512]

  pe_kernel<<<200, 256, 0, stream>>>(pe);
  cvt_kernel<<<(1572864 + 255) / 256, 256, 0, stream>>>(in_w, in_wb, 1572864);
  cvt_kernel<<<(524288 + 255) / 256, 256, 0, stream>>>(out_w, out_wb, 524288);
  cvt_kernel<<<(2097152 + 255) / 256, 256, 0, stream>>>(ff1_w, ff1_wb, 2097152);
  cvt_kernel<<<(2097152 + 255) / 256, 256, 0, stream>>>(ff2_w, ff2_wb, 2097152);

  // feature map + PE -> Xf (f32) and Xb (bf16 mirror)
  gemm_mfma<<<dim3(4, 400), 256, 0, stream>>>(
      x_data, 0L, 512, 64L, 6400L, feat_w, 64, feat_b, pe, 512,
      Xf, nullptr, Xb, 0L, 1 << 30, 0L, 512L, 1L, 512, 64, 0, 0);

  for (int l = 0; l < 2; ++l) {
    for (int c = 0; c < 4; ++c) {
      const long b0 = c * 128;
      // qkv chunk (bf16 in/out): rows rr=v*128+bl
      gemm_bf16<<<dim3(12, 100), 256, 0, stream>>>(
          Xb, b0 * 512, 128, 262144L, 512L,
          in_wb + (long)l * 786432, 512, in_b + l * 1536,
          nullptr, qkvb, 0L, 1 << 30, 0L, 1536L, 512, 0, 0);
      attn_kernel<<<dim3(8, 128), 256, 0, stream>>>(qkvb, ctxb);
      // x += ctx @ out_w^T + out_b  (scatter rows back)
      gemm_bf16<<<dim3(4, 100), 256, 0, stream>>>(
          ctxb, 0L, 1 << 30, 0L, 512L,
          out_wb + (long)l * 262144, 512, out_b + l * 512,
          Xf, nullptr, b0 * 512, 128, 262144L, 512L, 512, 1, 0);
    }
    ln_kernel<<<12800, 256, 0, stream>>>(Xf, Xb, ln1_g + l * 512, ln1_b + l * 512);
    for (int rc = 0; rc < 4; ++rc) {
      const long r0 = (long)rc * 12800;
      gemm_bf16<<<dim3(16, 100), 256, 0, stream>>>(
          Xb, r0 * 512, 1 << 30, 0L, 512L,
          ff1_wb + (long)l * 1048576, 512, ff1_b + l * 2048,
          nullptr, ffh, 0L, 1 << 30, 0L, 2048L, 512, 0, 1);
      gemm_bf16<<<dim3(4, 100), 256, 0, stream>>>(
          ffh, 0L, 1 << 30, 0L, 2048L,
          ff2_wb + (long)l * 1048576, 2048, ff2_b + l * 512,
          Xf, nullptr, r0 * 512, 1 << 30, 0L, 512L, 2048, 1, 0);
    }
    ln_kernel<<<12800, 256, 0, stream>>>(Xf, Xb, ln2_g + l * 512, ln2_b + l * 512);
  }

  // P[t][v][:] = h[t][v] @ att1_w[:, :512]^T (bf16 out) — reads fp32 Xf
  gemm_mfma<<<dim3(1, 400), 256, 0, stream>>>(
      Xf, 0L, 100, 512L, 262144L, att1_w, 768, nullptr, nullptr, 1,
      nullptr, PbB, nullptr, 0L, 1 << 30, 0L, 128L, 1L, 128, 512, 0, 0);
  // G[t][j][v] = (h[t][v] @ lstm_wih^T)[j] (bf16, transposed store)
  gemm_mfma<<<dim3(8, 400), 256, 0, stream>>>(
      Xf, 0L, 100, 512L, 262144L, lstm_wih, 512, nullptr, nullptr, 1,
      nullptr, GbB, nullptr, 0L, 100, 102400L, 1L, 100L, 1024, 512, 0, 0);

  init_kernel<<<1, 256, 0, stream>>>(s_h_slots, flags, c_g);
  decoder_kernel<<<DEC_NB, 256, 0, stream>>>(
      Xf, PbB, GbB, att1_w, att1_b, att2_w,
      lstm_whh, lstm_bih, lstm_bhh, fc1_w, fc1_b, fc2_w, fc2_b,
      s_h_slots, flags, c_g, (float*)d_out);
}